// Round 1
// baseline (791.737 us; speedup 1.0000x reference)
//
#include <hip/hip_runtime.h>

#define B_      8
#define N_      2048
#define DIM_    1024
#define HEADS_  8
#define CBD_    64
#define CBS_    1024
#define CBIN_   512              // HEADS_*CBD_
#define M_      (B_*N_)          // 16384 rows
#define M2_     (M_*HEADS_)      // 131072 row-heads

#define BK  16
#define LDP 132                  // padded LDS leading dim for GEMM tiles

// ---------------- e_sq precompute: esq[c] = sum_d embed[c][d]^2 ----------------
__global__ __launch_bounds__(256) void esq_kernel(const float* __restrict__ embed,
                                                  float* __restrict__ esq) {
    int c = blockIdx.x * 256 + threadIdx.x;
    if (c < CBS_) {
        const float* e = embed + (size_t)c * CBD_;
        float s = 0.f;
#pragma unroll
        for (int d = 0; d < CBD_; ++d) s += e[d] * e[d];
        esq[c] = s;
    }
}

// ---------------- GEMM1: h[M,512] = x[M,1024] @ W_in[1024,512] + b_in ----------------
// 128x128 tile, 256 threads, 8x8 per thread, BK=16, per-lane k rotation.
__global__ __launch_bounds__(256) void gemm_in(const float* __restrict__ A,
                                               const float* __restrict__ Bw,
                                               const float* __restrict__ bias,
                                               float* __restrict__ C) {
    __shared__ float As[BK][LDP];
    __shared__ float Bs[BK][LDP];
    const int tid = threadIdx.x;
    const int mg = tid & 15;      // row group 0..15
    const int ng = tid >> 4;      // col group 0..15
    const int m0 = blockIdx.y * 128;
    const int n0 = blockIdx.x * 128;
    const int K = DIM_, Nw = CBIN_;

    float acc[8][8];
#pragma unroll
    for (int r = 0; r < 8; ++r)
#pragma unroll
        for (int c = 0; c < 8; ++c) acc[r][c] = 0.f;

    for (int k0 = 0; k0 < K; k0 += BK) {
        __syncthreads();
        // stage A tile (128 rows x 16 k), stored transposed As[k][m]
#pragma unroll
        for (int s = 0; s < 2; ++s) {
            int f = tid + s * 256;
            int m = f >> 2, q = f & 3;
            float4 v = *(const float4*)(A + (size_t)(m0 + m) * K + k0 + q * 4);
            As[q * 4 + 0][m] = v.x; As[q * 4 + 1][m] = v.y;
            As[q * 4 + 2][m] = v.z; As[q * 4 + 3][m] = v.w;
        }
        // stage B tile (16 k x 128 n)
#pragma unroll
        for (int s = 0; s < 2; ++s) {
            int f = tid + s * 256;
            int k = f >> 5, nq = f & 31;
            float4 v = *(const float4*)(Bw + (size_t)(k0 + k) * Nw + n0 + nq * 4);
            *(float4*)&Bs[k][nq * 4] = v;
        }
        __syncthreads();
#pragma unroll
        for (int i = 0; i < BK; ++i) {
            int k = (i + mg) & 15;   // per-lane rotation: spreads LDS banks
            float4 a0 = *(const float4*)&As[k][mg * 8];
            float4 a1 = *(const float4*)&As[k][mg * 8 + 4];
            float4 b0 = *(const float4*)&Bs[k][ng * 8];
            float4 b1 = *(const float4*)&Bs[k][ng * 8 + 4];
            float a[8] = {a0.x, a0.y, a0.z, a0.w, a1.x, a1.y, a1.z, a1.w};
            float b[8] = {b0.x, b0.y, b0.z, b0.w, b1.x, b1.y, b1.z, b1.w};
#pragma unroll
            for (int r = 0; r < 8; ++r)
#pragma unroll
                for (int c = 0; c < 8; ++c) acc[r][c] += a[r] * b[c];
        }
    }
    // epilogue
#pragma unroll
    for (int r = 0; r < 8; ++r) {
        int m = m0 + mg * 8 + r;
        int n = n0 + ng * 8;
        float4 bb0 = *(const float4*)(bias + n);
        float4 bb1 = *(const float4*)(bias + n + 4);
        float4 o0 = {acc[r][0] + bb0.x, acc[r][1] + bb0.y, acc[r][2] + bb0.z, acc[r][3] + bb0.w};
        float4 o1 = {acc[r][4] + bb1.x, acc[r][5] + bb1.y, acc[r][6] + bb1.z, acc[r][7] + bb1.w};
        *(float4*)(C + (size_t)m * Nw + n) = o0;
        *(float4*)(C + (size_t)m * Nw + n + 4) = o1;
    }
}

// ---------------- argmax: per row-head, argmax_c 2*hx.e_c - |e_c|^2 ----------------
// 128 row-heads per block; embed streamed in 128-code chunks through LDS.
__global__ __launch_bounds__(256) void argmax_kernel(const float* __restrict__ h,
                                                     const float* __restrict__ embed,
                                                     const float* __restrict__ esq,
                                                     float* __restrict__ outIdxF,
                                                     int* __restrict__ outIdxI) {
    __shared__ float hxs[128 * 64];   // 32 KB, rows of hx (stride 64)
    __shared__ float ess[128 * 64];   // 32 KB, codebook chunk (stride 64)
    __shared__ float esqs[CBS_];      // 4 KB
    const int tid = threadIdx.x;
    const int rg = tid & 15;          // row group: rows rg*8..rg*8+7
    const int cg = tid >> 4;          // col group: cols cg*8..cg*8+7 within chunk
    const int r0 = blockIdx.x * 128;

    // stage hx rows (contiguous 32 KB) and esq
#pragma unroll
    for (int s = 0; s < 8; ++s) {
        int f = tid + s * 256;
        *(float4*)&hxs[f * 4] = *(const float4*)(h + (size_t)r0 * 64 + f * 4);
    }
    *(float4*)&esqs[tid * 4] = *(const float4*)(esq + tid * 4);

    float bestv[8];
    int   besti[8];
#pragma unroll
    for (int r = 0; r < 8; ++r) { bestv[r] = -3.4e38f; besti[r] = 0; }

    for (int ch = 0; ch < 8; ++ch) {
        __syncthreads();   // covers initial staging and protects ess reuse
#pragma unroll
        for (int s = 0; s < 8; ++s) {
            int f = tid + s * 256;
            *(float4*)&ess[f * 4] = *(const float4*)(embed + (size_t)ch * 128 * 64 + f * 4);
        }
        __syncthreads();
        float acc[8][8];
#pragma unroll
        for (int r = 0; r < 8; ++r)
#pragma unroll
            for (int c = 0; c < 8; ++c) acc[r][c] = 0.f;
#pragma unroll
        for (int i = 0; i < 16; ++i) {
            int d4 = ((i + rg) & 15) * 4;   // per-lane d rotation → conflict-free
            float4 ev[8];
#pragma unroll
            for (int c = 0; c < 8; ++c)
                ev[c] = *(const float4*)&ess[(cg * 8 + c) * 64 + d4];
#pragma unroll
            for (int r = 0; r < 8; ++r) {
                float4 hv = *(const float4*)&hxs[(rg * 8 + r) * 64 + d4];
#pragma unroll
                for (int c = 0; c < 8; ++c) {
                    acc[r][c] += hv.x * ev[c].x;
                    acc[r][c] += hv.y * ev[c].y;
                    acc[r][c] += hv.z * ev[c].z;
                    acc[r][c] += hv.w * ev[c].w;
                }
            }
        }
        // scores + running best (cols ascending within thread → first-max kept)
#pragma unroll
        for (int c = 0; c < 8; ++c) {
            int col = ch * 128 + cg * 8 + c;
            float eq = esqs[col];
#pragma unroll
            for (int r = 0; r < 8; ++r) {
                float sc = 2.f * acc[r][c] - eq;
                if (sc > bestv[r]) { bestv[r] = sc; besti[r] = col; }
            }
        }
    }
    // cross-cg reduction (overlay hxs; hx is dead now)
    __syncthreads();
    float* redv = hxs;                       // [16][128]
    int*   redi = (int*)(hxs + 16 * 128);    // [16][128]
#pragma unroll
    for (int r = 0; r < 8; ++r) {
        redv[cg * 128 + rg * 8 + r] = bestv[r];
        redi[cg * 128 + rg * 8 + r] = besti[r];
    }
    __syncthreads();
    if (tid < 128) {
        float bv = redv[tid];
        int   bi = redi[tid];
#pragma unroll
        for (int g = 1; g < 16; ++g) {
            float v = redv[g * 128 + tid];
            int  ii = redi[g * 128 + tid];
            if (v > bv || (v == bv && ii < bi)) { bv = v; bi = ii; }  // numpy tie-break: lowest idx
        }
        int m2 = r0 + tid;
        outIdxF[m2] = (float)bi;   // harness reads whole d_out as float32
        outIdxI[m2] = bi;
    }
}

// ---------------- GEMM3: out[M,1024] = gather(embed, idx)[M,512] @ W_out + b_out ----------------
__global__ __launch_bounds__(256) void gemm_out(const float* __restrict__ embed,
                                                const int* __restrict__ idx,
                                                const float* __restrict__ Bw,
                                                const float* __restrict__ bias,
                                                float* __restrict__ C) {
    __shared__ float As[BK][LDP];
    __shared__ float Bs[BK][LDP];
    __shared__ int idxs[128 * HEADS_];   // 1024 ints
    const int tid = threadIdx.x;
    const int mg = tid & 15;
    const int ng = tid >> 4;
    const int m0 = blockIdx.y * 128;
    const int n0 = blockIdx.x * 128;
    const int K = CBIN_, Nw = DIM_;

    // stage idx for this row block (contiguous)
    *(int4*)&idxs[tid * 4] = *(const int4*)(idx + (size_t)m0 * HEADS_ + tid * 4);

    float acc[8][8];
#pragma unroll
    for (int r = 0; r < 8; ++r)
#pragma unroll
        for (int c = 0; c < 8; ++c) acc[r][c] = 0.f;

    for (int k0 = 0; k0 < K; k0 += BK) {
        __syncthreads();   // first iteration: also covers idx staging
        int head = k0 >> 6;
        int dbase = k0 & 63;
#pragma unroll
        for (int s = 0; s < 2; ++s) {
            int f = tid + s * 256;
            int m = f >> 2, q = f & 3;
            int e = idxs[m * HEADS_ + head];
            float4 v = *(const float4*)(embed + (size_t)e * CBD_ + dbase + q * 4);
            As[q * 4 + 0][m] = v.x; As[q * 4 + 1][m] = v.y;
            As[q * 4 + 2][m] = v.z; As[q * 4 + 3][m] = v.w;
        }
#pragma unroll
        for (int s = 0; s < 2; ++s) {
            int f = tid + s * 256;
            int k = f >> 5, nq = f & 31;
            float4 v = *(const float4*)(Bw + (size_t)(k0 + k) * Nw + n0 + nq * 4);
            *(float4*)&Bs[k][nq * 4] = v;
        }
        __syncthreads();
#pragma unroll
        for (int i = 0; i < BK; ++i) {
            int k = (i + mg) & 15;
            float4 a0 = *(const float4*)&As[k][mg * 8];
            float4 a1 = *(const float4*)&As[k][mg * 8 + 4];
            float4 b0 = *(const float4*)&Bs[k][ng * 8];
            float4 b1 = *(const float4*)&Bs[k][ng * 8 + 4];
            float a[8] = {a0.x, a0.y, a0.z, a0.w, a1.x, a1.y, a1.z, a1.w};
            float b[8] = {b0.x, b0.y, b0.z, b0.w, b1.x, b1.y, b1.z, b1.w};
#pragma unroll
            for (int r = 0; r < 8; ++r)
#pragma unroll
                for (int c = 0; c < 8; ++c) acc[r][c] += a[r] * b[c];
        }
    }
#pragma unroll
    for (int r = 0; r < 8; ++r) {
        int m = m0 + mg * 8 + r;
        int n = n0 + ng * 8;
        float4 bb0 = *(const float4*)(bias + n);
        float4 bb1 = *(const float4*)(bias + n + 4);
        float4 o0 = {acc[r][0] + bb0.x, acc[r][1] + bb0.y, acc[r][2] + bb0.z, acc[r][3] + bb0.w};
        float4 o1 = {acc[r][4] + bb1.x, acc[r][5] + bb1.y, acc[r][6] + bb1.z, acc[r][7] + bb1.w};
        *(float4*)(C + (size_t)m * Nw + n) = o0;
        *(float4*)(C + (size_t)m * Nw + n + 4) = o1;
    }
}

extern "C" void kernel_launch(void* const* d_in, const int* in_sizes, int n_in,
                              void* d_out, int out_size, void* d_ws, size_t ws_size,
                              hipStream_t stream) {
    const float* x     = (const float*)d_in[0];
    const float* W_in  = (const float*)d_in[1];
    const float* b_in  = (const float*)d_in[2];
    const float* W_out = (const float*)d_in[3];
    const float* b_out = (const float*)d_in[4];
    const float* embed = (const float*)d_in[5];

    float* out     = (float*)d_out;
    float* outIdxF = out + (size_t)M_ * DIM_;          // 16,777,216 offset

    // workspace layout: h [M,512] fp32 (33.5 MB) | idx int32 [131072] | esq [1024]
    float* h    = (float*)d_ws;
    int*   idxI = (int*)((char*)d_ws + (size_t)M_ * CBIN_ * 4);
    float* esq  = (float*)((char*)d_ws + (size_t)M_ * CBIN_ * 4 + (size_t)M2_ * 4);

    esq_kernel<<<dim3(CBS_ / 256), dim3(256), 0, stream>>>(embed, esq);
    gemm_in<<<dim3(CBIN_ / 128, M_ / 128), dim3(256), 0, stream>>>(x, W_in, b_in, h);
    argmax_kernel<<<dim3(M2_ / 128), dim3(256), 0, stream>>>(h, embed, esq, outIdxF, idxI);
    gemm_out<<<dim3(DIM_ / 128, M_ / 128), dim3(256), 0, stream>>>(embed, idxI, W_out, b_out, out);
}

// Round 2
// 485.876 us; speedup vs baseline: 1.6295x; 1.6295x over previous
//
#include <hip/hip_runtime.h>

#define B_      8
#define N_      2048
#define DIM_    1024
#define HEADS_  8
#define CBD_    64
#define CBS_    1024
#define CBIN_   512              // HEADS_*CBD_
#define M_      (B_*N_)          // 16384 rows
#define M2_     (M_*HEADS_)      // 131072 row-heads

#define BK  16
#define LDP 132                  // padded LDS leading dim for fp32 GEMM tiles
#define MARGIN 0.02f             // >> deterministic bf16x3 score error bound (~2.4e-3)

typedef unsigned short ushort_t;
typedef __attribute__((ext_vector_type(8))) short short8;
typedef __attribute__((ext_vector_type(4))) float f32x4;

__device__ inline ushort_t f2bf(float f) {
    unsigned int u = __builtin_bit_cast(unsigned int, f);
    unsigned int r = u + 0x7FFFu + ((u >> 16) & 1u);
    return (ushort_t)(r >> 16);
}
__device__ inline float bf2f(ushort_t h) {
    unsigned int u = ((unsigned int)h) << 16;
    return __builtin_bit_cast(float, u);
}
__device__ inline f32x4 mfma_bf16(short8 a, short8 b, f32x4 c) {
    return __builtin_amdgcn_mfma_f32_16x16x32_bf16(a, b, c, 0, 0, 0);
}
__device__ inline void store4u(ushort_t* p, ushort_t a, ushort_t b, ushort_t c, ushort_t d) {
    uint2 u;
    u.x = (unsigned int)a | ((unsigned int)b << 16);
    u.y = (unsigned int)c | ((unsigned int)d << 16);
    *(uint2*)p = u;
}

// ---------------- prep: esq[c] = sum_d embed[c][d]^2 (fp32) ----------------
__global__ __launch_bounds__(256) void esq_kernel(const float* __restrict__ embed,
                                                  float* __restrict__ esq) {
    int c = blockIdx.x * 256 + threadIdx.x;
    if (c < CBS_) {
        const float* e = embed + (size_t)c * CBD_;
        float s = 0.f;
#pragma unroll
        for (int d = 0; d < CBD_; ++d) s += e[d] * e[d];
        esq[c] = s;
    }
}

// ---------------- prep: split embed into bf16 hi/lo ----------------
__global__ __launch_bounds__(256) void split_embed(const float* __restrict__ embed,
                                                   ushort_t* __restrict__ hi,
                                                   ushort_t* __restrict__ lo) {
    int i = blockIdx.x * 256 + threadIdx.x;   // 65536 total
    float f = embed[i];
    ushort_t h = f2bf(f);
    hi[i] = h;
    lo[i] = f2bf(f - bf2f(h));
}

// ---------------- prep: WbfT[n][k] = bf16(W_out[k][n]) ----------------
__global__ __launch_bounds__(256) void transposeW(const float* __restrict__ W,
                                                  ushort_t* __restrict__ WT) {
    __shared__ ushort_t t[64][65];
    const int tid = threadIdx.x;
    const int n0 = blockIdx.x * 64, k0 = blockIdx.y * 64;
#pragma unroll
    for (int s = 0; s < 16; ++s) {
        int i = s * 256 + tid;
        int r = i >> 6, c = i & 63;                 // r = k within tile, c = n within tile
        t[r][c] = f2bf(W[(size_t)(k0 + r) * DIM_ + n0 + c]);
    }
    __syncthreads();
#pragma unroll
    for (int s = 0; s < 16; ++s) {
        int i = s * 256 + tid;
        int r = i >> 6, c = i & 63;                 // r = n within tile, c = k within tile
        WT[(size_t)(n0 + r) * CBIN_ + k0 + c] = t[c][r];
    }
}

// ---------------- GEMM1 (fp32, unchanged): h[M,512] = x @ W_in + b_in ----------------
__global__ __launch_bounds__(256) void gemm_in(const float* __restrict__ A,
                                               const float* __restrict__ Bw,
                                               const float* __restrict__ bias,
                                               float* __restrict__ C) {
    __shared__ float As[BK][LDP];
    __shared__ float Bs[BK][LDP];
    const int tid = threadIdx.x;
    const int mg = tid & 15;
    const int ng = tid >> 4;
    const int m0 = blockIdx.y * 128;
    const int n0 = blockIdx.x * 128;
    const int K = DIM_, Nw = CBIN_;

    float acc[8][8];
#pragma unroll
    for (int r = 0; r < 8; ++r)
#pragma unroll
        for (int c = 0; c < 8; ++c) acc[r][c] = 0.f;

    for (int k0 = 0; k0 < K; k0 += BK) {
        __syncthreads();
#pragma unroll
        for (int s = 0; s < 2; ++s) {
            int f = tid + s * 256;
            int m = f >> 2, q = f & 3;
            float4 v = *(const float4*)(A + (size_t)(m0 + m) * K + k0 + q * 4);
            As[q * 4 + 0][m] = v.x; As[q * 4 + 1][m] = v.y;
            As[q * 4 + 2][m] = v.z; As[q * 4 + 3][m] = v.w;
        }
#pragma unroll
        for (int s = 0; s < 2; ++s) {
            int f = tid + s * 256;
            int k = f >> 5, nq = f & 31;
            float4 v = *(const float4*)(Bw + (size_t)(k0 + k) * Nw + n0 + nq * 4);
            *(float4*)&Bs[k][nq * 4] = v;
        }
        __syncthreads();
#pragma unroll
        for (int i = 0; i < BK; ++i) {
            int k = (i + mg) & 15;
            float4 a0 = *(const float4*)&As[k][mg * 8];
            float4 a1 = *(const float4*)&As[k][mg * 8 + 4];
            float4 b0 = *(const float4*)&Bs[k][ng * 8];
            float4 b1 = *(const float4*)&Bs[k][ng * 8 + 4];
            float a[8] = {a0.x, a0.y, a0.z, a0.w, a1.x, a1.y, a1.z, a1.w};
            float b[8] = {b0.x, b0.y, b0.z, b0.w, b1.x, b1.y, b1.z, b1.w};
#pragma unroll
            for (int r = 0; r < 8; ++r)
#pragma unroll
                for (int c = 0; c < 8; ++c) acc[r][c] += a[r] * b[c];
        }
    }
#pragma unroll
    for (int r = 0; r < 8; ++r) {
        int m = m0 + mg * 8 + r;
        int n = n0 + ng * 8;
        float4 bb0 = *(const float4*)(bias + n);
        float4 bb1 = *(const float4*)(bias + n + 4);
        float4 o0 = {acc[r][0] + bb0.x, acc[r][1] + bb0.y, acc[r][2] + bb0.z, acc[r][3] + bb0.w};
        float4 o1 = {acc[r][4] + bb1.x, acc[r][5] + bb1.y, acc[r][6] + bb1.z, acc[r][7] + bb1.w};
        *(float4*)(C + (size_t)m * Nw + n) = o0;
        *(float4*)(C + (size_t)m * Nw + n + 4) = o1;
    }
}

// ---------------- argmax via bf16x3 MFMA + margin + exact fp32 fallback ----------------
// Block: 128 row-heads, 4 waves x 32 rows. Codes streamed in 64-code chunks.
__global__ __launch_bounds__(256) void argmax2(const float* __restrict__ h,
                                               const ushort_t* __restrict__ embhi,
                                               const ushort_t* __restrict__ emblo,
                                               const float* __restrict__ esq,
                                               const float* __restrict__ embed,
                                               float* __restrict__ outIdxF,
                                               int* __restrict__ outIdxI) {
    __shared__ ushort_t HXHI[128 * 72];
    __shared__ ushort_t HXLO[128 * 72];
    __shared__ ushort_t EBHI[64 * 72];
    __shared__ ushort_t EBLO[64 * 72];
    __shared__ float    ESQ[CBS_];
    __shared__ int      BIDX[128];
    __shared__ int      FLAG[128];
    __shared__ int      NFLAG;

    const int tid  = threadIdx.x;
    const int lane = tid & 63;
    const int w    = tid >> 6;
    const int quad = lane >> 4;
    const int col  = lane & 15;
    const int r0   = blockIdx.x * 128;

    if (tid == 0) NFLAG = 0;

    // stage hx split (128 rows x 64 d), padded stride 72
#pragma unroll
    for (int s = 0; s < 8; ++s) {
        int f = s * 256 + tid;
        int row = f >> 4, q = f & 15;
        float4 v = *(const float4*)(h + (size_t)(r0 + row) * 64 + q * 4);
        float vv[4] = {v.x, v.y, v.z, v.w};
        ushort_t hi[4], lo[4];
#pragma unroll
        for (int j = 0; j < 4; ++j) {
            hi[j] = f2bf(vv[j]);
            lo[j] = f2bf(vv[j] - bf2f(hi[j]));
        }
        int base = row * 72 + q * 4;
        store4u(&HXHI[base], hi[0], hi[1], hi[2], hi[3]);
        store4u(&HXLO[base], lo[0], lo[1], lo[2], lo[3]);
    }
    *(float4*)&ESQ[tid * 4] = *(const float4*)(esq + tid * 4);
    __syncthreads();

    // hoist A-frags (row fragments): 2 row-tiles x 2 ksteps, hi+lo
    short8 AH[2][2], AL[2][2];
#pragma unroll
    for (int rt = 0; rt < 2; ++rt)
#pragma unroll
        for (int ks = 0; ks < 2; ++ks) {
            int m = w * 32 + rt * 16 + col;
            int offs = m * 72 + ks * 32 + quad * 8;
            AH[rt][ks] = *(const short8*)&HXHI[offs];
            AL[rt][ks] = *(const short8*)&HXLO[offs];
        }

    float v1[8], v2[8];
    int   i1[8];
#pragma unroll
    for (int s = 0; s < 8; ++s) { v1[s] = -3.4e38f; v2[s] = -3.4e38f; i1[s] = 0; }

    for (int ch = 0; ch < 16; ++ch) {
        __syncthreads();
        // stage 64-code chunk (hi+lo): 64 x 64 bf16 each
#pragma unroll
        for (int s = 0; s < 2; ++s) {
            int f = s * 256 + tid;
            int row = f >> 3, g = f & 7;
            *(uint4*)&EBHI[row * 72 + g * 8] =
                *(const uint4*)(embhi + (size_t)(ch * 64 + row) * 64 + g * 8);
            *(uint4*)&EBLO[row * 72 + g * 8] =
                *(const uint4*)(emblo + (size_t)(ch * 64 + row) * 64 + g * 8);
        }
        __syncthreads();
#pragma unroll
        for (int ct = 0; ct < 4; ++ct) {
            int nb = (ct * 16 + col) * 72 + quad * 8;
            short8 BH0 = *(const short8*)&EBHI[nb];
            short8 BH1 = *(const short8*)&EBHI[nb + 32];
            short8 BL0 = *(const short8*)&EBLO[nb];
            short8 BL1 = *(const short8*)&EBLO[nb + 32];
            int code = ch * 64 + ct * 16 + col;
            float eq = ESQ[code];
#pragma unroll
            for (int rt = 0; rt < 2; ++rt) {
                f32x4 acc = {0.f, 0.f, 0.f, 0.f};
                acc = mfma_bf16(AH[rt][0], BH0, acc);
                acc = mfma_bf16(AH[rt][1], BH1, acc);
                acc = mfma_bf16(AH[rt][0], BL0, acc);
                acc = mfma_bf16(AH[rt][1], BL1, acc);
                acc = mfma_bf16(AL[rt][0], BH0, acc);
                acc = mfma_bf16(AL[rt][1], BH1, acc);
#pragma unroll
                for (int reg = 0; reg < 4; ++reg) {
                    int st = rt * 4 + reg;
                    float sc = fmaf(2.f, acc[reg], -eq);
                    float losr = fminf(sc, v1[st]);
                    v2[st] = fmaxf(v2[st], losr);
                    bool gt = sc > v1[st];
                    v1[st] = fmaxf(v1[st], sc);
                    i1[st] = gt ? code : i1[st];
                }
            }
        }
    }

    // cross-lane merge over the 16 col-lanes (low 4 bits of lane)
#pragma unroll
    for (int st = 0; st < 8; ++st) {
#pragma unroll
        for (int m = 1; m <= 8; m <<= 1) {
            float ov1 = __shfl_xor(v1[st], m);
            int   oi1 = __shfl_xor(i1[st], m);
            float ov2 = __shfl_xor(v2[st], m);
            float losr = fminf(v1[st], ov1);
            v2[st] = fmaxf(fmaxf(v2[st], ov2), losr);
            bool take = (ov1 > v1[st]) || (ov1 == v1[st] && oi1 < i1[st]);
            v1[st] = take ? ov1 : v1[st];
            i1[st] = take ? oi1 : i1[st];
        }
        if (col == 0) {
            int rt = st >> 2, reg = st & 3;
            int row_l = w * 32 + rt * 16 + quad * 4 + reg;
            BIDX[row_l] = i1[st];
            if (v1[st] - v2[st] < MARGIN) {
                int p = atomicAdd(&NFLAG, 1);
                FLAG[p] = row_l;
            }
        }
    }
    __syncthreads();

    // exact fp32 fallback for ambiguous rows (rare: ~0.5%)
    int nf = NFLAG;
    for (int i = w; i < nf; i += 4) {
        int row_l = FLAG[i];
        const float* hr = h + (size_t)(r0 + row_l) * 64;
        float accf[16];
#pragma unroll
        for (int j = 0; j < 16; ++j) accf[j] = 0.f;
        for (int d4 = 0; d4 < 16; ++d4) {
            float4 hv = *(const float4*)(hr + d4 * 4);   // uniform across lanes
#pragma unroll
            for (int j = 0; j < 16; ++j) {
                int c = lane + 64 * j;
                float4 ev = *(const float4*)(embed + (size_t)c * 64 + d4 * 4);
                accf[j] += hv.x * ev.x + hv.y * ev.y + hv.z * ev.z + hv.w * ev.w;
            }
        }
        float best = -3.4e38f; int bi = 0;
#pragma unroll
        for (int j = 0; j < 16; ++j) {
            int c = lane + 64 * j;
            float sc = 2.f * accf[j] - ESQ[c];
            if (sc > best) { best = sc; bi = c; }   // ascending c within lane → first-max
        }
#pragma unroll
        for (int m = 1; m <= 32; m <<= 1) {
            float ob = __shfl_xor(best, m);
            int  obi = __shfl_xor(bi, m);
            if (ob > best || (ob == best && obi < bi)) { best = ob; bi = obi; }
        }
        if (lane == 0) BIDX[row_l] = bi;
    }
    __syncthreads();

    if (tid < 128) {
        int b = BIDX[tid];
        outIdxF[r0 + tid] = (float)b;
        outIdxI[r0 + tid] = b;
    }
}

// ---------------- GEMM3 (bf16 MFMA): out = gather(embhi, idx) @ W_out + b_out ----------------
// 128x128 block tile, 4 waves in 2x2, each wave 64x64 (4x4 MFMA 16x16x32 tiles), BK=64.
__global__ __launch_bounds__(256) void gemm_out_bf16(const ushort_t* __restrict__ embhi,
                                                     const int* __restrict__ idx,
                                                     const ushort_t* __restrict__ WbfT,
                                                     const float* __restrict__ bias,
                                                     float* __restrict__ C) {
    __shared__ ushort_t Qs[128 * 72];
    __shared__ ushort_t Ws[128 * 72];
    __shared__ int idxs[128 * HEADS_];

    const int tid  = threadIdx.x;
    const int lane = tid & 63;
    const int w    = tid >> 6;
    const int quad = lane >> 4;
    const int col  = lane & 15;
    const int m0   = blockIdx.y * 128;
    const int n0   = blockIdx.x * 128;
    const int wm   = (w & 1) * 64;
    const int wn   = (w >> 1) * 64;

#pragma unroll
    for (int s = 0; s < 4; ++s) {
        int f = s * 256 + tid;
        idxs[f] = idx[(size_t)m0 * HEADS_ + f];
    }

    f32x4 acc[4][4];
#pragma unroll
    for (int rt = 0; rt < 4; ++rt)
#pragma unroll
        for (int ct = 0; ct < 4; ++ct) acc[rt][ct] = (f32x4){0.f, 0.f, 0.f, 0.f};

    for (int k0 = 0; k0 < CBIN_; k0 += 64) {
        __syncthreads();   // first iter: also covers idxs staging
        int head = k0 >> 6;
#pragma unroll
        for (int s = 0; s < 4; ++s) {
            int f = s * 256 + tid;
            int row = f >> 3, g = f & 7;
            int e = idxs[row * HEADS_ + head];
            *(uint4*)&Qs[row * 72 + g * 8] = *(const uint4*)(embhi + (size_t)e * 64 + g * 8);
            *(uint4*)&Ws[row * 72 + g * 8] =
                *(const uint4*)(WbfT + (size_t)(n0 + row) * CBIN_ + k0 + g * 8);
        }
        __syncthreads();
#pragma unroll
        for (int ks = 0; ks < 2; ++ks) {
            short8 a[4], b[4];
#pragma unroll
            for (int rt = 0; rt < 4; ++rt)
                a[rt] = *(const short8*)&Qs[(wm + rt * 16 + col) * 72 + ks * 32 + quad * 8];
#pragma unroll
            for (int ct = 0; ct < 4; ++ct)
                b[ct] = *(const short8*)&Ws[(wn + ct * 16 + col) * 72 + ks * 32 + quad * 8];
#pragma unroll
            for (int rt = 0; rt < 4; ++rt)
#pragma unroll
                for (int ct = 0; ct < 4; ++ct)
                    acc[rt][ct] = mfma_bf16(a[rt], b[ct], acc[rt][ct]);
        }
    }

#pragma unroll
    for (int ct = 0; ct < 4; ++ct) {
        int gc = n0 + wn + ct * 16 + col;
        float bb = bias[gc];
#pragma unroll
        for (int rt = 0; rt < 4; ++rt) {
#pragma unroll
            for (int reg = 0; reg < 4; ++reg) {
                int gr = m0 + wm + rt * 16 + quad * 4 + reg;
                C[(size_t)gr * DIM_ + gc] = acc[rt][ct][reg] + bb;
            }
        }
    }
}

extern "C" void kernel_launch(void* const* d_in, const int* in_sizes, int n_in,
                              void* d_out, int out_size, void* d_ws, size_t ws_size,
                              hipStream_t stream) {
    const float* x     = (const float*)d_in[0];
    const float* W_in  = (const float*)d_in[1];
    const float* b_in  = (const float*)d_in[2];
    const float* W_out = (const float*)d_in[3];
    const float* b_out = (const float*)d_in[4];
    const float* embed = (const float*)d_in[5];

    float* out     = (float*)d_out;
    float* outIdxF = out + (size_t)M_ * DIM_;

    // workspace layout (35.4 MB total)
    char* ws = (char*)d_ws;
    float*    h     = (float*)ws;                                   // 33,554,432 B
    int*      idxI  = (int*)(ws + 33554432);                        //    524,288 B
    float*    esq   = (float*)(ws + 34078720);                      //      4,096 B
    ushort_t* embhi = (ushort_t*)(ws + 34082816);                   //    131,072 B
    ushort_t* emblo = (ushort_t*)(ws + 34213888);                   //    131,072 B
    ushort_t* WbfT  = (ushort_t*)(ws + 34344960);                   //  1,048,576 B

    esq_kernel<<<dim3(CBS_ / 256), dim3(256), 0, stream>>>(embed, esq);
    split_embed<<<dim3(CBS_ * CBD_ / 256), dim3(256), 0, stream>>>(embed, embhi, emblo);
    transposeW<<<dim3(DIM_ / 64, CBIN_ / 64), dim3(256), 0, stream>>>(W_out, WbfT);
    gemm_in<<<dim3(CBIN_ / 128, M_ / 128), dim3(256), 0, stream>>>(x, W_in, b_in, h);
    argmax2<<<dim3(M2_ / 128), dim3(256), 0, stream>>>(h, embhi, emblo, esq, embed,
                                                       outIdxF, idxI);
    gemm_out_bf16<<<dim3(DIM_ / 128, M_ / 128), dim3(256), 0, stream>>>(embhi, idxI, WbfT,
                                                                        b_out, out);
}

// Round 3
// 375.978 us; speedup vs baseline: 2.1058x; 1.2923x over previous
//
#include <hip/hip_runtime.h>

#define B_      8
#define N_      2048
#define DIM_    1024
#define HEADS_  8
#define CBD_    64
#define CBS_    1024
#define CBIN_   512              // HEADS_*CBD_
#define M_      (B_*N_)          // 16384 rows
#define M2_     (M_*HEADS_)      // 131072 row-heads

#define MARGIN 0.02f             // >> deterministic bf16x3 score error bound (~2.4e-3)
#define XSTR   40                // LDS stride (elements) for 32-k bf16 planes; 80 B = 16-B aligned

typedef unsigned short ushort_t;
typedef __attribute__((ext_vector_type(8))) short short8;
typedef __attribute__((ext_vector_type(4))) float f32x4;

__device__ inline ushort_t f2bf(float f) {
    unsigned int u = __builtin_bit_cast(unsigned int, f);
    unsigned int r = u + 0x7FFFu + ((u >> 16) & 1u);
    return (ushort_t)(r >> 16);
}
__device__ inline float bf2f(ushort_t h) {
    unsigned int u = ((unsigned int)h) << 16;
    return __builtin_bit_cast(float, u);
}
__device__ inline f32x4 mfma_bf16(short8 a, short8 b, f32x4 c) {
    return __builtin_amdgcn_mfma_f32_16x16x32_bf16(a, b, c, 0, 0, 0);
}
__device__ inline void store4u(ushort_t* p, ushort_t a, ushort_t b, ushort_t c, ushort_t d) {
    uint2 u;
    u.x = (unsigned int)a | ((unsigned int)b << 16);
    u.y = (unsigned int)c | ((unsigned int)d << 16);
    *(uint2*)p = u;
}
// 3-way bf16 split: f = s1 + s2 + s3 + O(2^-24 |f|)
__device__ inline void split3(float f, ushort_t& s1, ushort_t& s2, ushort_t& s3) {
    s1 = f2bf(f);
    float r = f - bf2f(s1);
    s2 = f2bf(r);
    float r2 = r - bf2f(s2);
    s3 = f2bf(r2);
}

// ---------------- prep: esq[c] = sum_d embed[c][d]^2 (fp32) ----------------
__global__ __launch_bounds__(256) void esq_kernel(const float* __restrict__ embed,
                                                  float* __restrict__ esq) {
    int c = blockIdx.x * 256 + threadIdx.x;
    if (c < CBS_) {
        const float* e = embed + (size_t)c * CBD_;
        float s = 0.f;
#pragma unroll
        for (int d = 0; d < CBD_; ++d) s += e[d] * e[d];
        esq[c] = s;
    }
}

// ---------------- prep: split embed into bf16 hi/lo ----------------
__global__ __launch_bounds__(256) void split_embed(const float* __restrict__ embed,
                                                   ushort_t* __restrict__ hi,
                                                   ushort_t* __restrict__ lo) {
    int i = blockIdx.x * 256 + threadIdx.x;   // 65536 total
    float f = embed[i];
    ushort_t h = f2bf(f);
    hi[i] = h;
    lo[i] = f2bf(f - bf2f(h));
}

// ---------------- prep: WbfT[n][k] = bf16(W_out[k][n]) ----------------
__global__ __launch_bounds__(256) void transposeW(const float* __restrict__ W,
                                                  ushort_t* __restrict__ WT) {
    __shared__ ushort_t t[64][65];
    const int tid = threadIdx.x;
    const int n0 = blockIdx.x * 64, k0 = blockIdx.y * 64;
#pragma unroll
    for (int s = 0; s < 16; ++s) {
        int i = s * 256 + tid;
        int r = i >> 6, c = i & 63;
        t[r][c] = f2bf(W[(size_t)(k0 + r) * DIM_ + n0 + c]);
    }
    __syncthreads();
#pragma unroll
    for (int s = 0; s < 16; ++s) {
        int i = s * 256 + tid;
        int r = i >> 6, c = i & 63;
        WT[(size_t)(n0 + r) * CBIN_ + k0 + c] = t[c][r];
    }
}

// ---------------- prep: 3-way split + transpose of W_in: WpT[n][k] ----------------
__global__ __launch_bounds__(256) void split_WinT(const float* __restrict__ W,
                                                  ushort_t* __restrict__ W1T,
                                                  ushort_t* __restrict__ W2T,
                                                  ushort_t* __restrict__ W3T) {
    __shared__ ushort_t t1[64][65];
    __shared__ ushort_t t2[64][65];
    __shared__ ushort_t t3[64][65];
    const int tid = threadIdx.x;
    const int n0 = blockIdx.x * 64, k0 = blockIdx.y * 64;
#pragma unroll
    for (int s = 0; s < 16; ++s) {
        int i = s * 256 + tid;
        int r = i >> 6, c = i & 63;                 // r = k in tile, c = n in tile
        float f = W[(size_t)(k0 + r) * CBIN_ + n0 + c];
        split3(f, t1[r][c], t2[r][c], t3[r][c]);
    }
    __syncthreads();
#pragma unroll
    for (int s = 0; s < 16; ++s) {
        int i = s * 256 + tid;
        int r = i >> 6, c = i & 63;                 // r = n in tile, c = k in tile
        size_t o = (size_t)(n0 + r) * DIM_ + k0 + c;
        W1T[o] = t1[c][r];
        W2T[o] = t2[c][r];
        W3T[o] = t3[c][r];
    }
}

// ---------------- GEMM1 via bf16x6 MFMA: h[M,512] = x @ W_in + b_in ----------------
// 128x128 tile, BK=32, 4 waves 2x2 (wave = 64x64 = 4x4 MFMA tiles of 16x16x32).
// x split 3-way in-kernel during staging; W_in planes pre-split (W1T/W2T/W3T, [n][k]).
__global__ __launch_bounds__(256) void gemm_in_x6(const float* __restrict__ x,
                                                  const ushort_t* __restrict__ W1T,
                                                  const ushort_t* __restrict__ W2T,
                                                  const ushort_t* __restrict__ W3T,
                                                  const float* __restrict__ bias,
                                                  float* __restrict__ C) {
    __shared__ ushort_t A1[128 * XSTR];
    __shared__ ushort_t A2[128 * XSTR];
    __shared__ ushort_t A3[128 * XSTR];
    __shared__ ushort_t B1[128 * XSTR];
    __shared__ ushort_t B2[128 * XSTR];
    __shared__ ushort_t B3[128 * XSTR];   // 6 * 10240 B = 61440 B

    const int tid  = threadIdx.x;
    const int lane = tid & 63;
    const int w    = tid >> 6;
    const int quad = lane >> 4;
    const int col  = lane & 15;
    const int m0   = blockIdx.y * 128;
    const int n0   = blockIdx.x * 128;
    const int wm   = (w & 1) * 64;
    const int wn   = (w >> 1) * 64;

    f32x4 acc[4][4];
#pragma unroll
    for (int rt = 0; rt < 4; ++rt)
#pragma unroll
        for (int ct = 0; ct < 4; ++ct) acc[rt][ct] = (f32x4){0.f, 0.f, 0.f, 0.f};

    for (int k0 = 0; k0 < DIM_; k0 += 32) {
        __syncthreads();
        // stage A: 128 rows x 32 k fp32 -> 3 bf16 planes (4 float4 per thread)
#pragma unroll
        for (int s = 0; s < 4; ++s) {
            int f = s * 256 + tid;
            int row = f >> 3, qq = f & 7;
            float4 v = *(const float4*)(x + (size_t)(m0 + row) * DIM_ + k0 + qq * 4);
            float vv[4] = {v.x, v.y, v.z, v.w};
            ushort_t p1[4], p2[4], p3[4];
#pragma unroll
            for (int j = 0; j < 4; ++j) split3(vv[j], p1[j], p2[j], p3[j]);
            int base = row * XSTR + qq * 4;
            store4u(&A1[base], p1[0], p1[1], p1[2], p1[3]);
            store4u(&A2[base], p2[0], p2[1], p2[2], p2[3]);
            store4u(&A3[base], p3[0], p3[1], p3[2], p3[3]);
        }
        // stage B planes: 128 n-rows x 32 k bf16 each (2 uint4 per thread per plane)
#pragma unroll
        for (int s = 0; s < 2; ++s) {
            int f = s * 256 + tid;
            int row = f >> 2, g = f & 3;
            size_t go = (size_t)(n0 + row) * DIM_ + k0 + g * 8;
            int lo = row * XSTR + g * 8;
            *(uint4*)&B1[lo] = *(const uint4*)(W1T + go);
            *(uint4*)&B2[lo] = *(const uint4*)(W2T + go);
            *(uint4*)&B3[lo] = *(const uint4*)(W3T + go);
        }
        __syncthreads();

        short8 a1[4], a2[4], a3[4], b1[4], b2[4], b3[4];
#pragma unroll
        for (int rt = 0; rt < 4; ++rt) {
            int o = (wm + rt * 16 + col) * XSTR + quad * 8;
            a1[rt] = *(const short8*)&A1[o];
            a2[rt] = *(const short8*)&A2[o];
            a3[rt] = *(const short8*)&A3[o];
        }
#pragma unroll
        for (int ct = 0; ct < 4; ++ct) {
            int o = (wn + ct * 16 + col) * XSTR + quad * 8;
            b1[ct] = *(const short8*)&B1[o];
            b2[ct] = *(const short8*)&B2[o];
            b3[ct] = *(const short8*)&B3[o];
        }
#define COMBO(AP, BP)                                                   \
        _Pragma("unroll")                                               \
        for (int ct = 0; ct < 4; ++ct)                                  \
            _Pragma("unroll")                                           \
            for (int rt = 0; rt < 4; ++rt)                              \
                acc[rt][ct] = mfma_bf16(AP[rt], BP[ct], acc[rt][ct]);
        COMBO(a1, b1); COMBO(a1, b2); COMBO(a2, b1);
        COMBO(a2, b2); COMBO(a1, b3); COMBO(a3, b1);
#undef COMBO
    }

#pragma unroll
    for (int ct = 0; ct < 4; ++ct) {
        int gc = n0 + wn + ct * 16 + col;
        float bb = bias[gc];
#pragma unroll
        for (int rt = 0; rt < 4; ++rt) {
#pragma unroll
            for (int reg = 0; reg < 4; ++reg) {
                int gr = m0 + wm + rt * 16 + quad * 4 + reg;
                C[(size_t)gr * CBIN_ + gc] = acc[rt][ct][reg] + bb;
            }
        }
    }
}

// ---------------- argmax via bf16x3 MFMA + margin + exact fp32 fallback ----------------
__global__ __launch_bounds__(256) void argmax2(const float* __restrict__ h,
                                               const ushort_t* __restrict__ embhi,
                                               const ushort_t* __restrict__ emblo,
                                               const float* __restrict__ esq,
                                               const float* __restrict__ embed,
                                               float* __restrict__ outIdxF,
                                               int* __restrict__ outIdxI) {
    __shared__ ushort_t HXHI[128 * 72];
    __shared__ ushort_t HXLO[128 * 72];
    __shared__ ushort_t EBHI[64 * 72];
    __shared__ ushort_t EBLO[64 * 72];
    __shared__ float    ESQ[CBS_];
    __shared__ int      BIDX[128];
    __shared__ int      FLAG[128];
    __shared__ int      NFLAG;

    const int tid  = threadIdx.x;
    const int lane = tid & 63;
    const int w    = tid >> 6;
    const int quad = lane >> 4;
    const int col  = lane & 15;
    const int r0   = blockIdx.x * 128;

    if (tid == 0) NFLAG = 0;

#pragma unroll
    for (int s = 0; s < 8; ++s) {
        int f = s * 256 + tid;
        int row = f >> 4, q = f & 15;
        float4 v = *(const float4*)(h + (size_t)(r0 + row) * 64 + q * 4);
        float vv[4] = {v.x, v.y, v.z, v.w};
        ushort_t hi[4], lo[4];
#pragma unroll
        for (int j = 0; j < 4; ++j) {
            hi[j] = f2bf(vv[j]);
            lo[j] = f2bf(vv[j] - bf2f(hi[j]));
        }
        int base = row * 72 + q * 4;
        store4u(&HXHI[base], hi[0], hi[1], hi[2], hi[3]);
        store4u(&HXLO[base], lo[0], lo[1], lo[2], lo[3]);
    }
    *(float4*)&ESQ[tid * 4] = *(const float4*)(esq + tid * 4);
    __syncthreads();

    short8 AH[2][2], AL[2][2];
#pragma unroll
    for (int rt = 0; rt < 2; ++rt)
#pragma unroll
        for (int ks = 0; ks < 2; ++ks) {
            int m = w * 32 + rt * 16 + col;
            int offs = m * 72 + ks * 32 + quad * 8;
            AH[rt][ks] = *(const short8*)&HXHI[offs];
            AL[rt][ks] = *(const short8*)&HXLO[offs];
        }

    float v1[8], v2[8];
    int   i1[8];
#pragma unroll
    for (int s = 0; s < 8; ++s) { v1[s] = -3.4e38f; v2[s] = -3.4e38f; i1[s] = 0; }

    for (int ch = 0; ch < 16; ++ch) {
        __syncthreads();
#pragma unroll
        for (int s = 0; s < 2; ++s) {
            int f = s * 256 + tid;
            int row = f >> 3, g = f & 7;
            *(uint4*)&EBHI[row * 72 + g * 8] =
                *(const uint4*)(embhi + (size_t)(ch * 64 + row) * 64 + g * 8);
            *(uint4*)&EBLO[row * 72 + g * 8] =
                *(const uint4*)(emblo + (size_t)(ch * 64 + row) * 64 + g * 8);
        }
        __syncthreads();
#pragma unroll
        for (int ct = 0; ct < 4; ++ct) {
            int nb = (ct * 16 + col) * 72 + quad * 8;
            short8 BH0 = *(const short8*)&EBHI[nb];
            short8 BH1 = *(const short8*)&EBHI[nb + 32];
            short8 BL0 = *(const short8*)&EBLO[nb];
            short8 BL1 = *(const short8*)&EBLO[nb + 32];
            int code = ch * 64 + ct * 16 + col;
            float eq = ESQ[code];
#pragma unroll
            for (int rt = 0; rt < 2; ++rt) {
                f32x4 acc = {0.f, 0.f, 0.f, 0.f};
                acc = mfma_bf16(AH[rt][0], BH0, acc);
                acc = mfma_bf16(AH[rt][1], BH1, acc);
                acc = mfma_bf16(AH[rt][0], BL0, acc);
                acc = mfma_bf16(AH[rt][1], BL1, acc);
                acc = mfma_bf16(AL[rt][0], BH0, acc);
                acc = mfma_bf16(AL[rt][1], BH1, acc);
#pragma unroll
                for (int reg = 0; reg < 4; ++reg) {
                    int st = rt * 4 + reg;
                    float sc = fmaf(2.f, acc[reg], -eq);
                    float losr = fminf(sc, v1[st]);
                    v2[st] = fmaxf(v2[st], losr);
                    bool gt = sc > v1[st];
                    v1[st] = fmaxf(v1[st], sc);
                    i1[st] = gt ? code : i1[st];
                }
            }
        }
    }

#pragma unroll
    for (int st = 0; st < 8; ++st) {
#pragma unroll
        for (int m = 1; m <= 8; m <<= 1) {
            float ov1 = __shfl_xor(v1[st], m);
            int   oi1 = __shfl_xor(i1[st], m);
            float ov2 = __shfl_xor(v2[st], m);
            float losr = fminf(v1[st], ov1);
            v2[st] = fmaxf(fmaxf(v2[st], ov2), losr);
            bool take = (ov1 > v1[st]) || (ov1 == v1[st] && oi1 < i1[st]);
            v1[st] = take ? ov1 : v1[st];
            i1[st] = take ? oi1 : i1[st];
        }
        if (col == 0) {
            int rt = st >> 2, reg = st & 3;
            int row_l = w * 32 + rt * 16 + quad * 4 + reg;
            BIDX[row_l] = i1[st];
            if (v1[st] - v2[st] < MARGIN) {
                int p = atomicAdd(&NFLAG, 1);
                FLAG[p] = row_l;
            }
        }
    }
    __syncthreads();

    int nf = NFLAG;
    for (int i = w; i < nf; i += 4) {
        int row_l = FLAG[i];
        const float* hr = h + (size_t)(r0 + row_l) * 64;
        float accf[16];
#pragma unroll
        for (int j = 0; j < 16; ++j) accf[j] = 0.f;
        for (int d4 = 0; d4 < 16; ++d4) {
            float4 hv = *(const float4*)(hr + d4 * 4);
#pragma unroll
            for (int j = 0; j < 16; ++j) {
                int c = lane + 64 * j;
                float4 ev = *(const float4*)(embed + (size_t)c * 64 + d4 * 4);
                accf[j] += hv.x * ev.x + hv.y * ev.y + hv.z * ev.z + hv.w * ev.w;
            }
        }
        float best = -3.4e38f; int bi = 0;
#pragma unroll
        for (int j = 0; j < 16; ++j) {
            int c = lane + 64 * j;
            float sc = 2.f * accf[j] - ESQ[c];
            if (sc > best) { best = sc; bi = c; }
        }
#pragma unroll
        for (int m = 1; m <= 32; m <<= 1) {
            float ob = __shfl_xor(best, m);
            int  obi = __shfl_xor(bi, m);
            if (ob > best || (ob == best && obi < bi)) { best = ob; bi = obi; }
        }
        if (lane == 0) BIDX[row_l] = bi;
    }
    __syncthreads();

    if (tid < 128) {
        int b = BIDX[tid];
        outIdxF[r0 + tid] = (float)b;
        outIdxI[r0 + tid] = b;
    }
}

// ---------------- GEMM3 (bf16 MFMA): out = gather(embhi, idx) @ W_out + b_out ----------------
__global__ __launch_bounds__(256) void gemm_out_bf16(const ushort_t* __restrict__ embhi,
                                                     const int* __restrict__ idx,
                                                     const ushort_t* __restrict__ WbfT,
                                                     const float* __restrict__ bias,
                                                     float* __restrict__ C) {
    __shared__ ushort_t Qs[128 * 72];
    __shared__ ushort_t Ws[128 * 72];
    __shared__ int idxs[128 * HEADS_];

    const int tid  = threadIdx.x;
    const int lane = tid & 63;
    const int w    = tid >> 6;
    const int quad = lane >> 4;
    const int col  = lane & 15;
    const int m0   = blockIdx.y * 128;
    const int n0   = blockIdx.x * 128;
    const int wm   = (w & 1) * 64;
    const int wn   = (w >> 1) * 64;

#pragma unroll
    for (int s = 0; s < 4; ++s) {
        int f = s * 256 + tid;
        idxs[f] = idx[(size_t)m0 * HEADS_ + f];
    }

    f32x4 acc[4][4];
#pragma unroll
    for (int rt = 0; rt < 4; ++rt)
#pragma unroll
        for (int ct = 0; ct < 4; ++ct) acc[rt][ct] = (f32x4){0.f, 0.f, 0.f, 0.f};

    for (int k0 = 0; k0 < CBIN_; k0 += 64) {
        __syncthreads();
        int head = k0 >> 6;
#pragma unroll
        for (int s = 0; s < 4; ++s) {
            int f = s * 256 + tid;
            int row = f >> 3, g = f & 7;
            int e = idxs[row * HEADS_ + head];
            *(uint4*)&Qs[row * 72 + g * 8] = *(const uint4*)(embhi + (size_t)e * 64 + g * 8);
            *(uint4*)&Ws[row * 72 + g * 8] =
                *(const uint4*)(WbfT + (size_t)(n0 + row) * CBIN_ + k0 + g * 8);
        }
        __syncthreads();
#pragma unroll
        for (int ks = 0; ks < 2; ++ks) {
            short8 a[4], b[4];
#pragma unroll
            for (int rt = 0; rt < 4; ++rt)
                a[rt] = *(const short8*)&Qs[(wm + rt * 16 + col) * 72 + ks * 32 + quad * 8];
#pragma unroll
            for (int ct = 0; ct < 4; ++ct)
                b[ct] = *(const short8*)&Ws[(wn + ct * 16 + col) * 72 + ks * 32 + quad * 8];
#pragma unroll
            for (int rt = 0; rt < 4; ++rt)
#pragma unroll
                for (int ct = 0; ct < 4; ++ct)
                    acc[rt][ct] = mfma_bf16(a[rt], b[ct], acc[rt][ct]);
        }
    }

#pragma unroll
    for (int ct = 0; ct < 4; ++ct) {
        int gc = n0 + wn + ct * 16 + col;
        float bb = bias[gc];
#pragma unroll
        for (int rt = 0; rt < 4; ++rt) {
#pragma unroll
            for (int reg = 0; reg < 4; ++reg) {
                int gr = m0 + wm + rt * 16 + quad * 4 + reg;
                C[(size_t)gr * DIM_ + gc] = acc[rt][ct][reg] + bb;
            }
        }
    }
}

extern "C" void kernel_launch(void* const* d_in, const int* in_sizes, int n_in,
                              void* d_out, int out_size, void* d_ws, size_t ws_size,
                              hipStream_t stream) {
    const float* x     = (const float*)d_in[0];
    const float* W_in  = (const float*)d_in[1];
    const float* b_in  = (const float*)d_in[2];
    const float* W_out = (const float*)d_in[3];
    const float* b_out = (const float*)d_in[4];
    const float* embed = (const float*)d_in[5];

    float* out     = (float*)d_out;
    float* outIdxF = out + (size_t)M_ * DIM_;

    // workspace layout (38.5 MB total)
    char* ws = (char*)d_ws;
    float*    h     = (float*)ws;                                   // 33,554,432 B
    int*      idxI  = (int*)(ws + 33554432);                        //    524,288 B
    float*    esq   = (float*)(ws + 34078720);                      //      4,096 B
    ushort_t* embhi = (ushort_t*)(ws + 34082816);                   //    131,072 B
    ushort_t* emblo = (ushort_t*)(ws + 34213888);                   //    131,072 B
    ushort_t* WbfT  = (ushort_t*)(ws + 34344960);                   //  1,048,576 B
    ushort_t* W1T   = (ushort_t*)(ws + 35393536);                   //  1,048,576 B
    ushort_t* W2T   = (ushort_t*)(ws + 36442112);                   //  1,048,576 B
    ushort_t* W3T   = (ushort_t*)(ws + 37490688);                   //  1,048,576 B

    esq_kernel<<<dim3(CBS_ / 256), dim3(256), 0, stream>>>(embed, esq);
    split_embed<<<dim3(CBS_ * CBD_ / 256), dim3(256), 0, stream>>>(embed, embhi, emblo);
    transposeW<<<dim3(DIM_ / 64, CBIN_ / 64), dim3(256), 0, stream>>>(W_out, WbfT);
    split_WinT<<<dim3(CBIN_ / 64, DIM_ / 64), dim3(256), 0, stream>>>(W_in, W1T, W2T, W3T);
    gemm_in_x6<<<dim3(CBIN_ / 128, M_ / 128), dim3(256), 0, stream>>>(x, W1T, W2T, W3T,
                                                                      b_in, h);
    argmax2<<<dim3(M2_ / 128), dim3(256), 0, stream>>>(h, embhi, emblo, esq, embed,
                                                       outIdxF, idxI);
    gemm_out_bf16<<<dim3(DIM_ / 128, M_ / 128), dim3(256), 0, stream>>>(embhi, idxI, WbfT,
                                                                        b_out, out);
}